// Round 2
// baseline (137.993 us; speedup 1.0000x reference)
//
#include <hip/hip_runtime.h>
#include <math.h>

namespace {

constexpr int SOUT = 12;    // (14-3)/1+1
constexpr int OCAP = 32;
constexpr int PD   = 16;    // 4x4 pose
constexpr int NI   = 288;   // 3*3*32
constexpr int SUBS = 4;     // i-dimension split factor
constexpr int ISUB = NI / SUBS;      // 72 input caps per block
constexpr int NPOS = 4 * SOUT * SOUT; // 576 output positions
constexpr float EPSF = 1e-9f;
constexpr int CHUNK = 33 * 32;       // per-(n,sub) partial: j*32+o ; j:0..15 S1, 16..31 S2, 32 S0
constexpr size_t POSE_OUT = (size_t)NPOS * OCAP * PD; // 294912

// One block = (position n, i-chunk sub). 256 threads, 4 waves.
// lane -> (o = lane&31, half = lane>>5); each wave-step processes 8 input caps.
template<int SWEEP>
__global__ __launch_bounds__(256, 4)
void sweep_kernel(const float* __restrict__ pose_in,   // [4,14,14,32,16]
                  const float* __restrict__ act_in,    // [4,14,14,32]
                  const float* __restrict__ wmat,      // [288,32,16]
                  const float* __restrict__ beta_v,    // [32]
                  const float* __restrict__ beta_a,    // [32]
                  const float* __restrict__ prev,      // partials of sweep-1 (unused if SWEEP==0)
                  float* __restrict__ outbuf)          // partials of this sweep
{
    __shared__ float sMean[OCAP][PD + 1];
    __shared__ float sInv2[OCAP][PD + 1];
    __shared__ float sBias[OCAP];                 // log(oact+EPS) - sum_d log(sigma+EPS)
    __shared__ float sRed[4][33][OCAP];           // per-wave partials

    const int bid = blockIdx.x;
    const int n   = bid >> 2;
    const int sub = bid & 3;
    const int b   = n / (SOUT * SOUT);
    const int yx  = n % (SOUT * SOUT);
    const int y   = yx / SOUT;
    const int x   = yx % SOUT;

    const int t    = threadIdx.x;
    const int wave = t >> 6;
    const int lane = t & 63;
    const int o    = lane & 31;
    const int half = lane >> 5;

    if constexpr (SWEEP > 0) {
        // redundantly finalize previous iteration's stats from the 4 sub-chunks
        const int oo = t >> 3, dp = t & 7, d0 = dp * 2;
        const float* base = prev + (size_t)n * (SUBS * CHUNK);
        float s0 = 0.f, S1a = 0.f, S1b = 0.f, S2a = 0.f, S2b = 0.f;
        #pragma unroll
        for (int s = 0; s < SUBS; ++s) {
            const float* c = base + s * CHUNK;
            s0  += c[32 * 32 + oo];
            S1a += c[(d0)      * 32 + oo];
            S1b += c[(d0 + 1)  * 32 + oo];
            S2a += c[(16 + d0) * 32 + oo];
            S2b += c[(17 + d0) * 32 + oo];
        }
        const float inv = 1.f / s0;
        const float m0 = S1a * inv, m1 = S1b * inv;
        const float v0 = fmaxf(fmaf(-m0, m0, S2a * inv), 0.f);
        const float v1 = fmaxf(fmaf(-m1, m1, S2b * inv), 0.f);
        const float lsum = __logf(sqrtf(v0) + EPSF) + __logf(sqrtf(v1) + EPSF);
        sMean[oo][d0] = m0;  sMean[oo][d0 + 1] = m1;
        sInv2[oo][d0] = 0.5f / fmaxf(v0, 1e-30f);
        sInv2[oo][d0 + 1] = 0.5f / fmaxf(v1, 1e-30f);
        float lt = lsum;
        lt += __shfl_xor(lt, 1, 8);
        lt += __shfl_xor(lt, 2, 8);
        lt += __shfl_xor(lt, 4, 8);
        if (dp == 0) {
            const float cost    = s0 * fmaf(16.f, beta_v[oo], lt);
            const float invtemp = (float)SWEEP;            // inv_temp of previous EM iter
            const float oact    = 1.f / (1.f + __expf(-invtemp * (beta_a[oo] - cost)));
            sBias[oo] = __logf(oact + EPSF) - lt;
        }
        __syncthreads();
    }

    float s1[PD], s2[PD];
    float s0acc = 0.f;
    #pragma unroll
    for (int d = 0; d < PD; ++d) { s1[d] = 0.f; s2[d] = 0.f; }

    #pragma unroll 1
    for (int step = 0; step < ISUB / 8; ++step) {
        const int i  = sub * ISUB + step * 8 + wave * 2 + half;
        const int k  = i >> 5;            // kernel cell 0..8
        const int c  = i & 31;            // input capsule within cell
        const int ki = k / 3, kj = k - ki * 3;
        const int cell = (b * 14 + y + ki) * 14 + (x + kj);

        // broadcast loads (same addr across the 32 lanes of a half) — L1/L2 hit
        const float* pr = pose_in + ((size_t)cell * 32 + c) * PD;
        const float a_i = act_in[(size_t)cell * 32 + c];
        float P[PD], W[PD];
        #pragma unroll
        for (int q4 = 0; q4 < 4; ++q4) {
            const float4 pv = *reinterpret_cast<const float4*>(&pr[q4 * 4]);
            P[q4*4+0] = pv.x; P[q4*4+1] = pv.y; P[q4*4+2] = pv.z; P[q4*4+3] = pv.w;
        }
        const float* wr = wmat + ((size_t)i * OCAP + o) * PD;
        #pragma unroll
        for (int q4 = 0; q4 < 4; ++q4) {
            const float4 wv = *reinterpret_cast<const float4*>(&wr[q4 * 4]);
            W[q4*4+0] = wv.x; W[q4*4+1] = wv.y; W[q4*4+2] = wv.z; W[q4*4+3] = wv.w;
        }

        // votes[p,r] = sum_q P[p,q] * W[q,r]
        float v[PD];
        #pragma unroll
        for (int p = 0; p < 4; ++p) {
            #pragma unroll
            for (int r = 0; r < 4; ++r) {
                float acc = P[p*4+0] * W[r];
                acc = fmaf(P[p*4+1], W[4  + r], acc);
                acc = fmaf(P[p*4+2], W[8  + r], acc);
                acc = fmaf(P[p*4+3], W[12 + r], acc);
                v[p*4+r] = acc;
            }
        }

        float rrp;
        if constexpr (SWEEP == 0) {
            rrp = a_i * (1.0f / 32.0f);                  // uniform rr = 1/O
        } else {
            float ts = 0.f;
            #pragma unroll
            for (int d = 0; d < PD; ++d) {
                const float diff = v[d] - sMean[o][d];
                ts = fmaf(diff * diff, sInv2[o][d], ts);
            }
            float zz = sBias[o] - ts;
            float m = zz;
            #pragma unroll
            for (int msk = 16; msk >= 1; msk >>= 1)
                m = fmaxf(m, __shfl_xor(m, msk, 32));
            const float e = __expf(zz - m);
            float es = e;
            #pragma unroll
            for (int msk = 16; msk >= 1; msk >>= 1)
                es += __shfl_xor(es, msk, 32);
            rrp = (e / es) * a_i;                        // rr * i_act
        }

        s0acc += rrp;
        #pragma unroll
        for (int d = 0; d < PD; ++d) {
            const float rv = rrp * v[d];
            s1[d] = fmaf(rrp, v[d], s1[d]);
            s2[d] = fmaf(rv, v[d], s2[d]);
        }
    }

    // fold the two halves (same o) within each wave
    #pragma unroll
    for (int d = 0; d < PD; ++d) {
        s1[d] += __shfl_xor(s1[d], 32, 64);
        s2[d] += __shfl_xor(s2[d], 32, 64);
    }
    s0acc += __shfl_xor(s0acc, 32, 64);

    if (half == 0) {
        #pragma unroll
        for (int d = 0; d < PD; ++d) {
            sRed[wave][d][o]      = s1[d];
            sRed[wave][16 + d][o] = s2[d];
        }
        sRed[wave][32][o] = s0acc;
    }
    __syncthreads();

    // cross-wave reduce + coalesced store of this block's partial chunk
    float* dst = outbuf + (size_t)bid * CHUNK;
    const int oc = t & 31;
    for (int j = t >> 5; j < 33; j += 8)
        dst[j * 32 + oc] = sRed[0][j][oc] + sRed[1][j][oc] + sRed[2][j][oc] + sRed[3][j][oc];
}

__global__ __launch_bounds__(256, 4)
void final_kernel(const float* __restrict__ prev,      // partials of sweep 2
                  const float* __restrict__ beta_v,
                  const float* __restrict__ beta_a,
                  float* __restrict__ out)
{
    const int n  = blockIdx.x;
    const int t  = threadIdx.x;
    const int oo = t >> 3, dp = t & 7, d0 = dp * 2;
    const float* base = prev + (size_t)n * (SUBS * CHUNK);
    float s0 = 0.f, S1a = 0.f, S1b = 0.f, S2a = 0.f, S2b = 0.f;
    #pragma unroll
    for (int s = 0; s < SUBS; ++s) {
        const float* c = base + s * CHUNK;
        s0  += c[32 * 32 + oo];
        S1a += c[(d0)      * 32 + oo];
        S1b += c[(d0 + 1)  * 32 + oo];
        S2a += c[(16 + d0) * 32 + oo];
        S2b += c[(17 + d0) * 32 + oo];
    }
    const float inv = 1.f / s0;
    const float m0 = S1a * inv, m1 = S1b * inv;
    out[(size_t)n * (OCAP * PD) + oo * PD + d0]     = m0;
    out[(size_t)n * (OCAP * PD) + oo * PD + d0 + 1] = m1;

    const float v0 = fmaxf(fmaf(-m0, m0, S2a * inv), 0.f);
    const float v1 = fmaxf(fmaf(-m1, m1, S2b * inv), 0.f);
    float lt = __logf(sqrtf(v0) + EPSF) + __logf(sqrtf(v1) + EPSF);
    lt += __shfl_xor(lt, 1, 8);
    lt += __shfl_xor(lt, 2, 8);
    lt += __shfl_xor(lt, 4, 8);
    if (dp == 0) {
        const float cost = s0 * fmaf(16.f, beta_v[oo], lt);
        const float oact = 1.f / (1.f + __expf(-3.0f * (beta_a[oo] - cost)));  // inv_temp=3 at it=2
        out[POSE_OUT + (size_t)n * OCAP + oo] = oact;
    }
}

} // namespace

extern "C" void kernel_launch(void* const* d_in, const int* in_sizes, int n_in,
                              void* d_out, int out_size, void* d_ws, size_t ws_size,
                              hipStream_t stream) {
    const float* pose_in = (const float*)d_in[0];
    const float* act_in  = (const float*)d_in[1];
    const float* wmat    = (const float*)d_in[2];
    const float* beta_v  = (const float*)d_in[3];
    const float* beta_a  = (const float*)d_in[4];
    float* out = (float*)d_out;

    float* bufA = (float*)d_ws;                       // 2304*1056 floats = 9.73 MB
    float* bufB = bufA + (size_t)NPOS * SUBS * CHUNK; // ping-pong

    dim3 block(256);
    dim3 gridS(NPOS * SUBS);   // 2304
    dim3 gridF(NPOS);          // 576

    sweep_kernel<0><<<gridS, block, 0, stream>>>(pose_in, act_in, wmat, beta_v, beta_a, nullptr, bufA);
    sweep_kernel<1><<<gridS, block, 0, stream>>>(pose_in, act_in, wmat, beta_v, beta_a, bufA, bufB);
    sweep_kernel<2><<<gridS, block, 0, stream>>>(pose_in, act_in, wmat, beta_v, beta_a, bufB, bufA);
    final_kernel<<<gridF, block, 0, stream>>>(bufA, beta_v, beta_a, out);
}